// Round 13
// baseline (1570.187 us; speedup 1.0000x reference)
//
#include <hip/hip_runtime.h>
#include <hip/hip_fp16.h>
#include <stdint.h>

typedef unsigned int uint;
typedef unsigned short ushort;
typedef unsigned char uchar;

#define NB 2048
#define NW 64
#define NF 128
#define NH 128

typedef __attribute__((ext_vector_type(8))) short s8v;
typedef __attribute__((ext_vector_type(8))) _Float16 h8v;
typedef __attribute__((ext_vector_type(4))) float f4v;
typedef __attribute__((ext_vector_type(2))) float f2v;
typedef __attribute__((ext_vector_type(2))) _Float16 h2v;
typedef __attribute__((ext_vector_type(2))) __fp16 p2v;

#define MFMA16(a, b, c) __builtin_amdgcn_mfma_f32_16x16x32_bf16((a), (b), (c), 0, 0, 0)
#define MFMAH(a, b, c)  __builtin_amdgcn_mfma_f32_16x16x32_f16((a), (b), (c), 0, 0, 0)
#define MFMA8(a, b, c)  __builtin_amdgcn_mfma_f32_16x16x32_fp8_fp8((a), (b), (c), 0, 0, 0)

union H8 { h8v v; __half2 h2[4]; h2v hx[4]; p2v px[4]; uint4 u4; uint2 u2[2]; ushort us[8]; };
union U8 { uint2 u2; long v; };

__device__ __forceinline__ float bfl(uint u){ return __uint_as_float(u << 16); }
__device__ __forceinline__ float bfh(uint u){ return __uint_as_float(u & 0xffff0000u); }
__device__ __forceinline__ float bf2f(ushort s){ return __uint_as_float(((uint)s) << 16); }
__device__ __forceinline__ ushort f2bf(float f){
  uint u = __float_as_uint(f);
  u += 0x7fffu + ((u >> 16) & 1u);
  return (ushort)(u >> 16);
}

__device__ __forceinline__ float fast_tanh(float x){
  float e = __expf(x + x);
  return 1.f - 2.f * __builtin_amdgcn_rcpf(e + 1.f);
}
__device__ __forceinline__ float fast_sig(float x){
  return __builtin_amdgcn_rcpf(1.f + __expf(-x));
}
// s' = f16(exp(2x - 1))  (pairs with E' = fp8(exp(2u + 1)))
__device__ __forceinline__ ushort expo_hm(float x){
  return __half_as_ushort(__float2half(__expf(x + x - 1.f)));
}
// E' = fp8 e4m3 of exp(2x + 1)
__device__ __forceinline__ uchar expo_fp8(float x){
  float e = __expf(x + x + 1.f);
  return (uchar)(__builtin_amdgcn_cvt_pk_fp8_f32(e, e, 0, false) & 0xff);
}
// pack 4 f32 -> 4 fp8 e4m3 bytes
__device__ __forceinline__ uint f2fp8x4(float a, float b, float c, float d){
  uint u = (uint)__builtin_amdgcn_cvt_pk_fp8_f32(a, b, 0, false);
  u = (uint)__builtin_amdgcn_cvt_pk_fp8_f32(c, d, (int)u, true);
  return u;
}
// decode 8 fp8 -> 8 f16
__device__ __forceinline__ H8 fp8x8_to_h8(uint2 ev){
  H8 r;
  f2v a = __builtin_amdgcn_cvt_pk_f32_fp8((int)ev.x, false);
  f2v b = __builtin_amdgcn_cvt_pk_f32_fp8((int)ev.x, true);
  f2v c = __builtin_amdgcn_cvt_pk_f32_fp8((int)ev.y, false);
  f2v d = __builtin_amdgcn_cvt_pk_f32_fp8((int)ev.y, true);
  r.px[0] = __builtin_amdgcn_cvt_pkrtz(a.x, a.y);
  r.px[1] = __builtin_amdgcn_cvt_pkrtz(b.x, b.y);
  r.px[2] = __builtin_amdgcn_cvt_pkrtz(c.x, c.y);
  r.px[3] = __builtin_amdgcn_cvt_pkrtz(d.x, d.y);
  return r;
}

__device__ __forceinline__ s8v packW(const float* p){
  s8v r;
  #pragma unroll
  for (int i = 0; i < 8; ++i) r[i] = (short)f2bf(p[i]);
  return r;
}

// ------- E_enc8: fp8(exp(2*upre + 1)) coalesced layout [b][ft8][kb2][lane64][8B] -------
__global__ __launch_bounds__(256) void k_upre(const float* __restrict__ X,
                                              const float* __restrict__ iaW1,
                                              uchar* __restrict__ E8){
  __shared__ __align__(16) float sXT[128*68];
  __shared__ __align__(16) uchar sOut[8192];
  const int tid = threadIdx.x, lane = tid & 63, wave = tid >> 6, g = lane >> 4;
  int b = blockIdx.x;
  const float* Xb = X + (size_t)b*NW*NF;
  for (int i = tid; i < NW*NF; i += 256){
    int j = i >> 7, f = i & 127;
    sXT[f*68 + j] = Xb[i];
  }
  s8v bw[2];
  {
    int w = wave*16 + (lane & 15);
    #pragma unroll
    for (int kb = 0; kb < 2; ++kb) bw[kb] = packW(iaW1 + w*320 + kb*32 + g*8);
  }
  __syncthreads();
  int w = wave*16 + (lane & 15);
  #pragma unroll
  for (int mt = 0; mt < 8; ++mt){
    int f0 = mt*16 + (lane & 15);
    f4v acc = {0.f,0.f,0.f,0.f};
    #pragma unroll
    for (int kb = 0; kb < 2; ++kb){
      const float* p = &sXT[f0*68 + kb*32 + g*8];
      s8v a;
      #pragma unroll
      for (int i = 0; i < 8; ++i) a[i] = (short)f2bf(p[i]);
      acc = MFMA16(a, bw[kb], acc);
    }
    int fr = mt*16 + g*4;
    #pragma unroll
    for (int j = 0; j < 4; ++j){
      int f = fr + j;
      sOut[mt*1024 + (w>>5)*512 + (((w>>3)&3)*16 + (f&15))*8 + (w&7)] = expo_fp8(acc[j]);
    }
  }
  __syncthreads();
  uchar* outb = E8 + (size_t)b*8192;
  *(uint4*)(outb + tid*32)      = *(const uint4*)(sOut + tid*32);
  *(uint4*)(outb + tid*32 + 16) = *(const uint4*)(sOut + tid*32 + 16);
}

// ------- E_dec8: fp8(exp(2*vpre + 1)) layout [b][wt4][kb4][lane64][8B]; HsT8 fp8(16*Hs^T) -------
__global__ __launch_bounds__(256) void k_vpre(const ushort* __restrict__ Hsb,
                                              const float* __restrict__ taW1,
                                              uchar* __restrict__ E8,
                                              uchar* __restrict__ HsT8){
  __shared__ __align__(16) ushort sH[64*136];
  __shared__ __align__(16) uchar sOut[8192];
  const int tid = threadIdx.x, lane = tid & 63, wave = tid >> 6, g = lane >> 4;
  int b = blockIdx.x;
  const ushort* Hb = Hsb + (size_t)b*NW*NH;
  for (int i = tid; i < 1024; i += 256){
    int w = i >> 4, c = i & 15;
    *(uint4*)&sH[w*136 + c*8] = *(const uint4*)(Hb + i*8);
  }
  s8v bw[2][4];
  #pragma unroll
  for (int nt = 0; nt < 2; ++nt){
    int h = wave*32 + nt*16 + (lane & 15);
    #pragma unroll
    for (int kb = 0; kb < 4; ++kb)
      bw[nt][kb] = packW(taW1 + h*384 + kb*32 + g*8);
  }
  __syncthreads();
  uchar* ho = HsT8 + (size_t)b*NH*NW;
  for (int k = 0; k < 8; ++k){
    int s = tid + 256*k;
    int h = s >> 4, w0 = (s & 15)*4;
    float f0 = bf2f(sH[(w0+0)*136 + h])*16.f;
    float f1 = bf2f(sH[(w0+1)*136 + h])*16.f;
    float f2 = bf2f(sH[(w0+2)*136 + h])*16.f;
    float f3 = bf2f(sH[(w0+3)*136 + h])*16.f;
    *(uint*)(ho + h*64 + w0) = f2fp8x4(f0, f1, f2, f3);
  }
  #pragma unroll
  for (int mt = 0; mt < 4; ++mt){
    s8v af[4];
    #pragma unroll
    for (int kb = 0; kb < 4; ++kb)
      af[kb] = *(const s8v*)&sH[(mt*16 + (lane&15))*136 + kb*32 + g*8];
    #pragma unroll
    for (int nt = 0; nt < 2; ++nt){
      f4v acc = {0.f,0.f,0.f,0.f};
      #pragma unroll
      for (int kb = 0; kb < 4; ++kb) acc = MFMA16(af[kb], bw[nt][kb], acc);
      int h = wave*32 + nt*16 + (lane&15);
      int wr = mt*16 + g*4;
      #pragma unroll
      for (int j = 0; j < 4; ++j){
        int w2_ = wr + j;
        sOut[(w2_>>4)*2048 + (h>>5)*512 + (((h>>3)&3)*16 + (w2_&15))*8 + (h&7)] = expo_fp8(acc[j]);
      }
    }
  }
  __syncthreads();
  uchar* outb = E8 + (size_t)b*8192;
  *(uint4*)(outb + tid*32)      = *(const uint4*)(sOut + tid*32);
  *(uint4*)(outb + tid*32 + 16) = *(const uint4*)(sOut + tid*32 + 16);
}

// =========================== encoder: 256 blocks x 8 batches (r11 base, E from global) ===========================
__global__ __launch_bounds__(512, 2) void k_enc(
    const float* __restrict__ X, const float* __restrict__ iaW1,
    const float* __restrict__ iab1, const float* __restrict__ iaW2,
    const float* __restrict__ encWih, const float* __restrict__ encWhh,
    const float* __restrict__ encbih, const float* __restrict__ encbhh,
    const uchar* __restrict__ Eenc8, ushort* __restrict__ Hsb){
  __shared__ __align__(16) ushort sAB[16*264];   // [c|h] bf16
  __shared__ __align__(16) ushort sXt[16*264];   // xt bf16
  __shared__ __align__(16) ushort uhc_h[8*64];   // exp(2*uhc-1) f16
  __shared__ __align__(16) float  xrow[8*128];   // wave-private X row

  const int tid = threadIdx.x, lane = tid & 63, wave = tid >> 6, g = lane >> 4;
  const int bbase = blockIdx.x * 8;
  const int n16 = wave*16 + (lane & 15);

  for (int i = tid; i < 16*264; i += 512){ sAB[i] = 0; sXt[i] = 0; }
  float bias_r[4];
  #pragma unroll
  for (int gg = 0; gg < 4; ++gg)
    bias_r[gg] = encbih[gg*128 + n16] + encbhh[gg*128 + n16];
  float b1_r = iab1[n16 & 63];
  float c_r[4] = {0.f, 0.f, 0.f, 0.f};
  s8v bwC[4][8];
  #pragma unroll
  for (int gg = 0; gg < 4; ++gg){
    int j = gg*128 + n16;
    #pragma unroll
    for (int kc = 0; kc < 8; ++kc){
      const float* p = (kc < 4) ? (encWih + j*128 + kc*32) : (encWhh + j*128 + (kc-4)*32);
      bwC[gg][kc] = packW(p + g*8);
    }
  }
  s8v bwA[8];
  if (wave < 4){
    #pragma unroll
    for (int kc = 0; kc < 8; ++kc){
      int col = (kc < 4) ? (192 + kc*32) : (64 + (kc-4)*32);
      bwA[kc] = packW(iaW1 + n16*320 + col + g*8);
    }
  }
  H8 w2f[2];
  #pragma unroll
  for (int kb = 0; kb < 2; ++kb)
    #pragma unroll
    for (int i = 0; i < 8; ++i)
      w2f[kb].v[i] = (_Float16)iaW2[kb*32 + g*8 + i];
  {
    const float* Xr = X + ((size_t)(bbase + wave)*NW + 0)*NF;
    xrow[wave*128 + lane] = Xr[lane];
    xrow[wave*128 + 64 + lane] = Xr[64 + lane];
  }
  __syncthreads();

  const uchar* Eb = Eenc8 + (size_t)(bbase + wave)*8192;   // wave = batch

  for (int t = 0; t < NW; ++t){
    float xn0, xn1;
    {
      int tn = (t + 1) & 63;
      const float* Xr = X + ((size_t)(bbase + wave)*NW + tn)*NF;
      xn0 = Xr[lane];
      xn1 = Xr[64 + lane];
    }
    // ---- A: read [c|h]; waves 0-3: uhc via MFMA, store exp(2*uhc-1) f16 ----
    s8v aT[8];
    #pragma unroll
    for (int kc = 0; kc < 8; ++kc)
      aT[kc] = *(const s8v*)((const char*)sAB + (lane&15)*528 + kc*64 + g*16);
    if (wave < 4){
      f4v acc = {0.f,0.f,0.f,0.f};
      #pragma unroll
      for (int kc = 0; kc < 8; ++kc) acc = MFMA16(aT[kc], bwA[kc], acc);
      if (lane < 32){
        int mb = g*4;
        #pragma unroll
        for (int j = 0; j < 4; ++j) uhc_h[(mb+j)*64 + n16] = expo_hm(acc[j] + b1_r);
      }
    }
    __syncthreads();  // 1

    // ---- B: M[f] via fp8-global + f16 rcp + MFMAH; no-max softmax; write xt -> sXt ----
    {
      int bb = wave;
      H8 sv[2];
      #pragma unroll
      for (int kb = 0; kb < 2; ++kb)
        sv[kb].u4 = *(const uint4*)((const char*)uhc_h + bb*128 + kb*64 + g*16);
      __half2 one2 = __float2half2_rn(1.f);
      f4v Mc[8];
      #pragma unroll
      for (int ft = 0; ft < 8; ++ft){
        f4v acc = {0.f,0.f,0.f,0.f};
        #pragma unroll
        for (int kb = 0; kb < 2; ++kb){
          uint2 ev = *(const uint2*)(Eb + ft*1024 + kb*512 + lane*8);
          H8 e = fp8x8_to_h8(ev);
          H8 a;
          #pragma unroll
          for (int q = 0; q < 4; ++q) a.h2[q] = h2rcp(__hfma2(e.h2[q], sv[kb].h2[q], one2));
          acc = MFMAH(a.v, w2f[kb].v, acc);
        }
        Mc[ft] = acc;
      }
      float xs[8][4]; float ssum = 0.f;
      #pragma unroll
      for (int ft = 0; ft < 8; ++ft)
        #pragma unroll
        for (int r = 0; r < 4; ++r){ float x = __expf(-2.f*Mc[ft][r]); xs[ft][r] = x; ssum += x; }
      ssum += __shfl_xor(ssum, 16, 64);
      ssum += __shfl_xor(ssum, 32, 64);
      float inv = __builtin_amdgcn_rcpf(ssum);
      if ((lane & 15) == 0){
        #pragma unroll
        for (int ft = 0; ft < 8; ++ft){
          int f0 = ft*16 + g*4;
          float4 Xv = *(const float4*)&xrow[bb*128 + f0];
          uint lo = (uint)f2bf(xs[ft][0]*inv*Xv.x) | ((uint)f2bf(xs[ft][1]*inv*Xv.y) << 16);
          uint hi = (uint)f2bf(xs[ft][2]*inv*Xv.z) | ((uint)f2bf(xs[ft][3]*inv*Xv.w) << 16);
          *(uint2*)((char*)sXt + bb*528 + f0*2) = make_uint2(lo, hi);
        }
      }
    }
    __syncthreads();  // 2

    // ---- gates via MFMA (aX from sXt); in-wave LSTM update ----
    {
      s8v aX[4];
      #pragma unroll
      for (int kc = 0; kc < 4; ++kc)
        aX[kc] = *(const s8v*)((const char*)sXt + (lane&15)*528 + kc*64 + g*16);
      f4v acc[4];
      #pragma unroll
      for (int gg = 0; gg < 4; ++gg) acc[gg] = (f4v){0.f,0.f,0.f,0.f};
      #pragma unroll
      for (int kc = 0; kc < 8; ++kc){
        s8v af = (kc < 4) ? aX[kc] : aT[kc];
        #pragma unroll
        for (int gg = 0; gg < 4; ++gg) acc[gg] = MFMA16(af, bwC[gg][kc], acc[gg]);
      }
      if (lane < 32){
        int mb = g*4;
        #pragma unroll
        for (int j = 0; j < 4; ++j){
          int m = mb + j;
          float gi = acc[0][j] + bias_r[0];
          float gf = acc[1][j] + bias_r[1];
          float gg2 = acc[2][j] + bias_r[2];
          float go = acc[3][j] + bias_r[3];
          float cold = c_r[j];
          float cn = fast_sig(gf)*cold + fast_sig(gi)*fast_tanh(gg2);
          float hn = fast_sig(go)*fast_tanh(cn);
          c_r[j] = cn;
          sAB[m*264 + n16] = f2bf(cn);
          sAB[m*264 + 128 + n16] = f2bf(hn);
          Hsb[((size_t)(bbase + m)*NW + t)*NH + n16] = f2bf(hn);
        }
      }
      xrow[wave*128 + lane] = xn0;
      xrow[wave*128 + 64 + lane] = xn1;
    }
    __syncthreads();  // 3
  }
}

// =========================== decoder: 256 blocks x 8 batches (r11 base, E from global) ===========================
__global__ __launch_bounds__(512, 2) void k_dec(
    const float* __restrict__ taW1, const float* __restrict__ tab1,
    const float* __restrict__ taW2,
    const float* __restrict__ decWih, const float* __restrict__ decWhh,
    const float* __restrict__ decbih, const float* __restrict__ decbhh,
    const float* __restrict__ l1W, const float* __restrict__ l1b,
    const float* __restrict__ l2W, const float* __restrict__ l2b,
    const float* __restrict__ l3W, const float* __restrict__ l3b,
    const uchar* __restrict__ Edec8, const uchar* __restrict__ HsT8,
    float* __restrict__ out){
  __shared__ __align__(16) ushort sAB[16*264];   // [d|ds] bf16
  __shared__ __align__(16) ushort sCT[16*136];   // ct bf16
  __shared__ __align__(16) ushort vd_h[8*128];   // exp(2*vd-1) f16
  __shared__ __align__(16) uchar  lb8[8*64];     // beta*16 fp8
  __shared__ __align__(16) float  op_s[8][8];    // per-wave l3.o partials
  __shared__ __align__(16) float  yt_s[8];

  const int tid = threadIdx.x, lane = tid & 63, wave = tid >> 6, g = lane >> 4;
  const int bbase = blockIdx.x * 8;
  const int n16 = wave*16 + (lane & 15);

  for (int i = tid; i < 16*264; i += 512) sAB[i] = 0;
  for (int i = tid; i < 16*136; i += 512) sCT[i] = 0;
  float bias_r[4], wih_r[4];
  #pragma unroll
  for (int gg = 0; gg < 4; ++gg){
    bias_r[gg] = decbih[gg*128 + n16] + decbhh[gg*128 + n16];
    wih_r[gg]  = decWih[gg*128 + n16];
  }
  float tab1_r = tab1[n16];
  float l2b_r  = l2b[n16];
  float l3w_r  = l3W[n16];
  float l1w0 = l1W[0], l1b0 = l1b[0], l3b0 = l3b[0];
  float cds_r[4] = {0.f, 0.f, 0.f, 0.f};
  s8v bwA[8];
  #pragma unroll
  for (int kc = 0; kc < 8; ++kc)
    bwA[kc] = packW(taW1 + n16*384 + 128 + kc*32 + g*8);
  s8v bwD[4][4];
  #pragma unroll
  for (int gg = 0; gg < 4; ++gg){
    int j = gg*128 + n16;
    #pragma unroll
    for (int kc = 0; kc < 4; ++kc)
      bwD[gg][kc] = packW(decWhh + j*128 + kc*32 + g*8);
  }
  s8v bwF[8];
  #pragma unroll
  for (int kc = 0; kc < 8; ++kc)
    bwF[kc] = packW(l2W + n16*256 + kc*32 + g*8);
  H8 w2df[4];
  #pragma unroll
  for (int kb = 0; kb < 4; ++kb)
    #pragma unroll
    for (int i = 0; i < 8; ++i)
      w2df[kb].v[i] = (_Float16)taW2[kb*32 + g*8 + i];
  float l1w[8];
  #pragma unroll
  for (int ht = 0; ht < 8; ++ht) l1w[ht] = l1W[1 + ht*16 + (lane & 15)];
  __syncthreads();

  const uchar* Eb  = Edec8 + (size_t)(bbase + wave)*8192;   // wave = batch
  const uchar* hb8 = HsT8 + (size_t)(bbase + wave)*NH*NW;

  for (int t = 0; t < NW; ++t){
    // ---- A: vd via MFMA from [d|ds]; store exp(2*vd-1) f16 ----
    s8v aT[8];
    #pragma unroll
    for (int kc = 0; kc < 8; ++kc)
      aT[kc] = *(const s8v*)((const char*)sAB + (lane&15)*528 + kc*64 + g*16);
    {
      f4v acc = {0.f,0.f,0.f,0.f};
      #pragma unroll
      for (int kc = 0; kc < 8; ++kc) acc = MFMA16(aT[kc], bwA[kc], acc);
      if (lane < 32){
        int mb = g*4;
        #pragma unroll
        for (int j = 0; j < 4; ++j) vd_h[(mb+j)*128 + n16] = expo_hm(acc[j] + tab1_r);
      }
    }
    __syncthreads();  // 1

    // ---- B+C (wave-local): softmax over w (E fp8 global), ct (fp8 MFMA) + yt ----
    {
      int bb = wave;
      U8 hbf[8][2];
      #pragma unroll
      for (int ht = 0; ht < 8; ++ht){
        int h = ht*16 + (lane & 15);
        hbf[ht][0].u2 = *(const uint2*)(hb8 + h*64 + g*8);
        hbf[ht][1].u2 = *(const uint2*)(hb8 + h*64 + 32 + g*8);
      }
      H8 sv[4];
      #pragma unroll
      for (int kb = 0; kb < 4; ++kb)
        sv[kb].u4 = *(const uint4*)((const char*)vd_h + bb*256 + kb*64 + g*16);
      __half2 one2 = __float2half2_rn(1.f);
      f4v Mc[4];
      #pragma unroll
      for (int wt = 0; wt < 4; ++wt){
        f4v acc = {0.f,0.f,0.f,0.f};
        #pragma unroll
        for (int kb = 0; kb < 4; ++kb){
          uint2 ev = *(const uint2*)(Eb + wt*2048 + kb*512 + lane*8);
          H8 e = fp8x8_to_h8(ev);
          H8 a;
          #pragma unroll
          for (int q = 0; q < 4; ++q) a.h2[q] = h2rcp(__hfma2(e.h2[q], sv[kb].h2[q], one2));
          acc = MFMAH(a.v, w2df[kb].v, acc);
        }
        Mc[wt] = acc;
      }
      float xs[4][4]; float ssum = 0.f;
      #pragma unroll
      for (int wt = 0; wt < 4; ++wt)
        #pragma unroll
        for (int r = 0; r < 4; ++r){ float x = __expf(-2.f*Mc[wt][r]); xs[wt][r] = x; ssum += x; }
      ssum += __shfl_xor(ssum, 16, 64);
      ssum += __shfl_xor(ssum, 32, 64);
      float inv16 = 16.f * __builtin_amdgcn_rcpf(ssum);
      if ((lane & 15) == 0){
        #pragma unroll
        for (int wt = 0; wt < 4; ++wt){
          int w0 = wt*16 + g*4;
          *(uint*)(lb8 + bb*64 + w0) =
            f2fp8x4(xs[wt][0]*inv16, xs[wt][1]*inv16, xs[wt][2]*inv16, xs[wt][3]*inv16);
        }
      }
      U8 ba0, ba1;
      ba0.u2 = *(const uint2*)(lb8 + bb*64 + g*8);
      ba1.u2 = *(const uint2*)(lb8 + bb*64 + 32 + g*8);
      float p = 0.f;
      #pragma unroll
      for (int ht = 0; ht < 8; ++ht){
        f4v acc = {0.f,0.f,0.f,0.f};
        acc = MFMA8(ba0.v, hbf[ht][0].v, acc);
        acc = MFMA8(ba1.v, hbf[ht][1].v, acc);
        float ctv = acc[0] * (1.f/256.f);
        if (lane < 16) sCT[bb*136 + ht*16 + (lane&15)] = f2bf(ctv);
        p += l1w[ht] * ctv;
      }
      p += __shfl_xor(p, 1, 64);
      p += __shfl_xor(p, 2, 64);
      p += __shfl_xor(p, 4, 64);
      p += __shfl_xor(p, 8, 64);
      if (lane == 0) yt_s[bb] = p + l1b0;
    }
    __syncthreads();  // 2

    // ---- D: gates via MFMA + in-wave update (out_prev from op_s) ----
    {
      f4v g4[4];
      #pragma unroll
      for (int gg = 0; gg < 4; ++gg) g4[gg] = (f4v){0.f,0.f,0.f,0.f};
      #pragma unroll
      for (int kc = 0; kc < 4; ++kc){
        #pragma unroll
        for (int gg = 0; gg < 4; ++gg) g4[gg] = MFMA16(aT[kc], bwD[gg][kc], g4[gg]);
      }
      if (lane < 32){
        int mb = g*4;
        float4 so = make_float4(0.f, 0.f, 0.f, 0.f);
        #pragma unroll
        for (int w = 0; w < 8; ++w){
          float4 v = *(const float4*)((const char*)op_s + w*32 + g*16);
          so.x += v.x; so.y += v.y; so.z += v.z; so.w += v.w;
        }
        float soa[4] = {so.x, so.y, so.z, so.w};
        #pragma unroll
        for (int j = 0; j < 4; ++j){
          int m = mb + j;
          float outp = (t == 0) ? 0.f : fast_sig(soa[j] + l3b0);
          float yt = yt_s[m] + l1w0*outp;
          float gi = g4[0][j] + bias_r[0] + wih_r[0]*yt;
          float gf = g4[1][j] + bias_r[1] + wih_r[1]*yt;
          float gg2 = g4[2][j] + bias_r[2] + wih_r[2]*yt;
          float go = g4[3][j] + bias_r[3] + wih_r[3]*yt;
          float cold = cds_r[j];
          float cn = fast_sig(gf)*cold + fast_sig(gi)*fast_tanh(gg2);
          float hn = fast_sig(go)*fast_tanh(cn);
          cds_r[j] = cn;
          sAB[m*264 + n16] = f2bf(hn);
          sAB[m*264 + 128 + n16] = f2bf(cn);
        }
      }
    }
    __syncthreads();  // 3

    // ---- F: o = [ct|d_new] @ l2W^T + l2b via MFMA; l3.o partials ----
    {
      f4v of = {0.f,0.f,0.f,0.f};
      #pragma unroll
      for (int kc = 0; kc < 4; ++kc){
        s8v af = *(const s8v*)((const char*)sCT + (lane&15)*272 + kc*64 + g*16);
        of = MFMA16(af, bwF[kc], of);
      }
      #pragma unroll
      for (int kc = 4; kc < 8; ++kc){
        s8v af = *(const s8v*)((const char*)sAB + (lane&15)*528 + (kc-4)*64 + g*16);
        of = MFMA16(af, bwF[kc], of);
      }
      float p0 = l3w_r*(of[0] + l2b_r);
      float p1 = l3w_r*(of[1] + l2b_r);
      float p2 = l3w_r*(of[2] + l2b_r);
      float p3 = l3w_r*(of[3] + l2b_r);
      #pragma unroll
      for (int off = 1; off <= 8; off <<= 1){
        p0 += __shfl_xor(p0, off, 64);
        p1 += __shfl_xor(p1, off, 64);
        p2 += __shfl_xor(p2, off, 64);
        p3 += __shfl_xor(p3, off, 64);
      }
      if ((lane & 15) == 0 && lane < 32){
        *(float4*)((char*)op_s + wave*32 + g*16) = make_float4(p0, p1, p2, p3);
      }
    }
    // no trailing barrier: op_s consumed after bar1+bar2 of t+1
  }
  __syncthreads();
  if (tid < 8){
    float s = 0.f;
    #pragma unroll
    for (int w = 0; w < 8; ++w) s += op_s[w][tid];
    out[bbase + tid] = fast_sig(s + l3b0);
  }
}

extern "C" void kernel_launch(void* const* d_in, const int* in_sizes, int n_in,
                              void* d_out, int out_size, void* d_ws, size_t ws_size,
                              hipStream_t stream){
  const float* X      = (const float*)d_in[0];
  const float* iaW1   = (const float*)d_in[1];
  const float* iab1   = (const float*)d_in[2];
  const float* iaW2   = (const float*)d_in[3];
  const float* encWih = (const float*)d_in[5];
  const float* encWhh = (const float*)d_in[6];
  const float* encbih = (const float*)d_in[7];
  const float* encbhh = (const float*)d_in[8];
  const float* taW1   = (const float*)d_in[9];
  const float* tab1   = (const float*)d_in[10];
  const float* taW2   = (const float*)d_in[11];
  const float* decWih = (const float*)d_in[13];
  const float* decWhh = (const float*)d_in[14];
  const float* decbih = (const float*)d_in[15];
  const float* decbhh = (const float*)d_in[16];
  const float* l1W    = (const float*)d_in[17];
  const float* l1b    = (const float*)d_in[18];
  const float* l2W    = (const float*)d_in[19];
  const float* l2b    = (const float*)d_in[20];
  const float* l3W    = (const float*)d_in[21];
  const float* l3b    = (const float*)d_in[22];

  char* ws = (char*)d_ws;
  uchar*  Eenc8 = (uchar*)(ws);                // 16MB fp8 coalesced; aliased by Edec8 later
  ushort* Hsb   = (ushort*)(ws + 33554432);    // 32MB bf16 [b][w][h]
  uchar*  HsT8  = (uchar*)(ws + 2*33554432);   // 16MB fp8 [b][h][w] (x16)
  uchar*  Edec8 = Eenc8;

  k_upre<<<dim3(2048), dim3(256), 0, stream>>>(X, iaW1, Eenc8);
  k_enc<<<dim3(256), dim3(512), 0, stream>>>(X, iaW1, iab1, iaW2,
                                             encWih, encWhh, encbih, encbhh,
                                             Eenc8, Hsb);
  k_vpre<<<dim3(2048), dim3(256), 0, stream>>>(Hsb, taW1, Edec8, HsT8);
  k_dec<<<dim3(256), dim3(512), 0, stream>>>(taW1, tab1, taW2,
                                             decWih, decWhh, decbih, decbhh,
                                             l1W, l1b, l2W, l2b, l3W, l3b,
                                             Edec8, HsT8, (float*)d_out);
}

// Round 14
// 946.581 us; speedup vs baseline: 1.6588x; 1.6588x over previous
//
#include <hip/hip_runtime.h>
#include <hip/hip_fp16.h>
#include <stdint.h>

typedef unsigned int uint;
typedef unsigned short ushort;
typedef unsigned char uchar;

#define NB 2048
#define NW 64
#define NF 128
#define NH 128

typedef __attribute__((ext_vector_type(8))) short s8v;
typedef __attribute__((ext_vector_type(8))) _Float16 h8v;
typedef __attribute__((ext_vector_type(4))) float f4v;

#define MFMA16(a, b, c) __builtin_amdgcn_mfma_f32_16x16x32_bf16((a), (b), (c), 0, 0, 0)
#define MFMAH(a, b, c)  __builtin_amdgcn_mfma_f32_16x16x32_f16((a), (b), (c), 0, 0, 0)
#define MFMA8(a, b, c)  __builtin_amdgcn_mfma_f32_16x16x32_fp8_fp8((a), (b), (c), 0, 0, 0)

union H8 { h8v v; __half2 h2[4]; uint4 u4; ushort us[8]; };
union U8 { uint2 u2; long v; };

__device__ __forceinline__ float bfl(uint u){ return __uint_as_float(u << 16); }
__device__ __forceinline__ float bfh(uint u){ return __uint_as_float(u & 0xffff0000u); }
__device__ __forceinline__ float bf2f(ushort s){ return __uint_as_float(((uint)s) << 16); }
__device__ __forceinline__ ushort f2bf(float f){
  uint u = __float_as_uint(f);
  u += 0x7fffu + ((u >> 16) & 1u);
  return (ushort)(u >> 16);
}

__device__ __forceinline__ float fast_tanh(float x){
  float e = __expf(x + x);
  return 1.f - 2.f * __builtin_amdgcn_rcpf(e + 1.f);
}
__device__ __forceinline__ float fast_sig(float x){
  return __builtin_amdgcn_rcpf(1.f + __expf(-x));
}
__device__ __forceinline__ ushort expo_h(float x){  // f16 bits of exp(2x)
  return __half_as_ushort(__float2half(__expf(x + x)));
}
// pack 4 f32 -> 4 fp8 e4m3 bytes
__device__ __forceinline__ uint f2fp8x4(float a, float b, float c, float d){
  uint u = (uint)__builtin_amdgcn_cvt_pk_fp8_f32(a, b, 0, false);
  u = (uint)__builtin_amdgcn_cvt_pk_fp8_f32(c, d, (int)u, true);
  return u;
}

__device__ __forceinline__ s8v packW(const float* p){
  s8v r;
  #pragma unroll
  for (int i = 0; i < 8; ++i) r[i] = (short)f2bf(p[i]);
  return r;
}

// ------- E_enc[b][f][w] = f16(exp(2 * sum_j ia_W1[w,j]*X[b,j,f])), MFMA -------
__global__ __launch_bounds__(256) void k_upre(const float* __restrict__ X,
                                              const float* __restrict__ iaW1,
                                              ushort* __restrict__ Eenc){
  __shared__ __align__(16) float sXT[128*68];
  const int tid = threadIdx.x, lane = tid & 63, wave = tid >> 6, g = lane >> 4;
  int b = blockIdx.x;
  const float* Xb = X + (size_t)b*NW*NF;
  for (int i = tid; i < NW*NF; i += 256){
    int j = i >> 7, f = i & 127;
    sXT[f*68 + j] = Xb[i];
  }
  s8v bw[2];
  {
    int w = wave*16 + (lane & 15);
    #pragma unroll
    for (int kb = 0; kb < 2; ++kb) bw[kb] = packW(iaW1 + w*320 + kb*32 + g*8);
  }
  __syncthreads();
  ushort* outb = Eenc + (size_t)b*NF*NW;
  int w = wave*16 + (lane & 15);
  #pragma unroll
  for (int mt = 0; mt < 8; ++mt){
    int f = mt*16 + (lane & 15);
    f4v acc = {0.f,0.f,0.f,0.f};
    #pragma unroll
    for (int kb = 0; kb < 2; ++kb){
      const float* p = &sXT[f*68 + kb*32 + g*8];
      s8v a;
      #pragma unroll
      for (int i = 0; i < 8; ++i) a[i] = (short)f2bf(p[i]);
      acc = MFMA16(a, bw[kb], acc);
    }
    int fr = mt*16 + g*4;
    #pragma unroll
    for (int j = 0; j < 4; ++j) outb[(fr + j)*64 + w] = expo_h(acc[j]);
  }
}

// ------- E_dec[b][w][h] = f16(exp(2*vpre)) via MFMA; HsT8[b][h][w] = fp8(16*Hs^T) -------
__global__ __launch_bounds__(256) void k_vpre(const ushort* __restrict__ Hsb,
                                              const float* __restrict__ taW1,
                                              ushort* __restrict__ Edec,
                                              uchar* __restrict__ HsT8){
  __shared__ __align__(16) ushort sH[64*136];
  const int tid = threadIdx.x, lane = tid & 63, wave = tid >> 6, g = lane >> 4;
  int b = blockIdx.x;
  const ushort* Hb = Hsb + (size_t)b*NW*NH;
  for (int i = tid; i < 1024; i += 256){
    int w = i >> 4, c = i & 15;
    *(uint4*)&sH[w*136 + c*8] = *(const uint4*)(Hb + i*8);
  }
  s8v bw[2][4];
  #pragma unroll
  for (int nt = 0; nt < 2; ++nt){
    int h = wave*32 + nt*16 + (lane & 15);
    #pragma unroll
    for (int kb = 0; kb < 4; ++kb)
      bw[nt][kb] = packW(taW1 + h*384 + kb*32 + g*8);
  }
  __syncthreads();
  // transpose + fp8(x16): HsT8[h][w]
  uchar* ho = HsT8 + (size_t)b*NH*NW;
  for (int k = 0; k < 8; ++k){
    int s = tid + 256*k;            // 2048 slots x 4B
    int h = s >> 4, w0 = (s & 15)*4;
    float f0 = bf2f(sH[(w0+0)*136 + h])*16.f;
    float f1 = bf2f(sH[(w0+1)*136 + h])*16.f;
    float f2 = bf2f(sH[(w0+2)*136 + h])*16.f;
    float f3 = bf2f(sH[(w0+3)*136 + h])*16.f;
    *(uint*)(ho + h*64 + w0) = f2fp8x4(f0, f1, f2, f3);
  }
  ushort* outb = Edec + (size_t)b*NW*NH;
  for (int k = 0; k < 16; ++k){
    // handled below via MFMA loop
    break;
  }
  #pragma unroll
  for (int mt = 0; mt < 4; ++mt){
    s8v af[4];
    #pragma unroll
    for (int kb = 0; kb < 4; ++kb)
      af[kb] = *(const s8v*)&sH[(mt*16 + (lane&15))*136 + kb*32 + g*8];
    #pragma unroll
    for (int nt = 0; nt < 2; ++nt){
      f4v acc = {0.f,0.f,0.f,0.f};
      #pragma unroll
      for (int kb = 0; kb < 4; ++kb) acc = MFMA16(af[kb], bw[nt][kb], acc);
      int h = wave*32 + nt*16 + (lane&15);
      int wr = mt*16 + g*4;
      #pragma unroll
      for (int j = 0; j < 4; ++j) outb[(wr + j)*128 + h] = expo_h(acc[j]);
    }
  }
}

// =========================== encoder (r6-proven structure) ===========================
__global__ __launch_bounds__(512, 2) void k_enc(
    const float* __restrict__ X, const float* __restrict__ iaW1,
    const float* __restrict__ iab1, const float* __restrict__ iaW2,
    const float* __restrict__ encWih, const float* __restrict__ encWhh,
    const float* __restrict__ encbih, const float* __restrict__ encbhh,
    const ushort* __restrict__ Eenc, ushort* __restrict__ Hsb){
  __shared__ __align__(16) ushort sUp[65536];    // E_enc slice [bb][f][w] f16, slot-XOR
  __shared__ __align__(16) ushort sAB[16*264];   // A-tile [c|h] bf16
  __shared__ __align__(16) ushort sXt[16*264];   // A-tile xt bf16
  __shared__ __align__(16) ushort uhc_h[8*64];   // exp(2*uhc) f16
  __shared__ __align__(16) float  xrow[8*128];   // wave-private X row

  const int tid = threadIdx.x, lane = tid & 63, wave = tid >> 6, g = lane >> 4;
  const int bbase = blockIdx.x * 8;
  const int n16 = wave*16 + (lane & 15);

  for (int i = tid; i < 16*264; i += 512){ sAB[i] = 0; sXt[i] = 0; }
  {
    const ushort* up0 = Eenc + (size_t)bbase*NF*NW;
    #pragma unroll
    for (int k = 0; k < 16; ++k){
      int c = tid + k*512;
      int f = (c >> 3) & 127, s = c & 7;
      uint4 v = *(const uint4*)(up0 + (size_t)c*8);
      *(uint4*)((char*)sUp + (c>>3)*128 + ((s ^ (f & 7)) << 4)) = v;
    }
  }
  float bias_r[4];
  #pragma unroll
  for (int gg = 0; gg < 4; ++gg)
    bias_r[gg] = encbih[gg*128 + n16] + encbhh[gg*128 + n16];
  float b1_r = iab1[n16 & 63];
  float c_r[4] = {0.f, 0.f, 0.f, 0.f};
  s8v bwC[4][8];
  #pragma unroll
  for (int gg = 0; gg < 4; ++gg){
    int j = gg*128 + n16;
    #pragma unroll
    for (int kc = 0; kc < 8; ++kc){
      const float* p = (kc < 4) ? (encWih + j*128 + kc*32) : (encWhh + j*128 + (kc-4)*32);
      bwC[gg][kc] = packW(p + g*8);
    }
  }
  s8v bwA[8];
  if (wave < 4){
    #pragma unroll
    for (int kc = 0; kc < 8; ++kc){
      int col = (kc < 4) ? (192 + kc*32) : (64 + (kc-4)*32);
      bwA[kc] = packW(iaW1 + n16*320 + col + g*8);
    }
  }
  H8 w2f[2];
  #pragma unroll
  for (int kb = 0; kb < 2; ++kb)
    #pragma unroll
    for (int i = 0; i < 8; ++i)
      w2f[kb].v[i] = (_Float16)iaW2[kb*32 + g*8 + i];
  {
    const float* Xr = X + ((size_t)(bbase + wave)*NW + 0)*NF;
    xrow[wave*128 + lane] = Xr[lane];
    xrow[wave*128 + 64 + lane] = Xr[64 + lane];
  }
  __syncthreads();

  for (int t = 0; t < NW; ++t){
    float xn0, xn1;
    {
      int tn = (t + 1) & 63;
      const float* Xr = X + ((size_t)(bbase + wave)*NW + tn)*NF;
      xn0 = Xr[lane];
      xn1 = Xr[64 + lane];
    }
    // ---- A: read [c|h]; waves 0-3: uhc via MFMA ----
    s8v aT[8];
    #pragma unroll
    for (int kc = 0; kc < 8; ++kc)
      aT[kc] = *(const s8v*)((const char*)sAB + (lane&15)*528 + kc*64 + g*16);
    if (wave < 4){
      f4v acc = {0.f,0.f,0.f,0.f};
      #pragma unroll
      for (int kc = 0; kc < 8; ++kc) acc = MFMA16(aT[kc], bwA[kc], acc);
      if (lane < 32){
        int mb = g*4;
        #pragma unroll
        for (int j = 0; j < 4; ++j) uhc_h[(mb+j)*64 + n16] = expo_h(acc[j] + b1_r);
      }
    }
    __syncthreads();  // 1

    // ---- B: M[f] via f16 rcp + MFMAH; no-max softmax; write xt -> sXt ----
    {
      int bb = wave;
      const char* Eb = (const char*)sUp + bb*16384;
      H8 sv[2];
      #pragma unroll
      for (int kb = 0; kb < 2; ++kb)
        sv[kb].u4 = *(const uint4*)((const char*)uhc_h + bb*128 + kb*64 + g*16);
      __half2 one2 = __float2half2_rn(1.f);
      f4v Mc[8];
      #pragma unroll
      for (int ft = 0; ft < 8; ++ft){
        int f = ft*16 + (lane & 15);
        const char* rowp = Eb + f*128;
        f4v acc = {0.f,0.f,0.f,0.f};
        #pragma unroll
        for (int kb = 0; kb < 2; ++kb){
          H8 e, a;
          e.v = *(const h8v*)(rowp + (((kb*4 + g) ^ (f & 7)) << 4));
          #pragma unroll
          for (int q = 0; q < 4; ++q) a.h2[q] = h2rcp(__hfma2(e.h2[q], sv[kb].h2[q], one2));
          acc = MFMAH(a.v, w2f[kb].v, acc);
        }
        Mc[ft] = acc;
      }
      float xs[8][4]; float ssum = 0.f;
      #pragma unroll
      for (int ft = 0; ft < 8; ++ft)
        #pragma unroll
        for (int r = 0; r < 4; ++r){ float x = __expf(-2.f*Mc[ft][r]); xs[ft][r] = x; ssum += x; }
      ssum += __shfl_xor(ssum, 16, 64);
      ssum += __shfl_xor(ssum, 32, 64);
      float inv = __builtin_amdgcn_rcpf(ssum);
      if ((lane & 15) == 0){
        #pragma unroll
        for (int ft = 0; ft < 8; ++ft){
          int f0 = ft*16 + g*4;
          float4 Xv = *(const float4*)&xrow[bb*128 + f0];
          uint lo = (uint)f2bf(xs[ft][0]*inv*Xv.x) | ((uint)f2bf(xs[ft][1]*inv*Xv.y) << 16);
          uint hi = (uint)f2bf(xs[ft][2]*inv*Xv.z) | ((uint)f2bf(xs[ft][3]*inv*Xv.w) << 16);
          *(uint2*)((char*)sXt + bb*528 + f0*2) = make_uint2(lo, hi);
        }
      }
    }
    __syncthreads();  // 2

    // ---- gates via MFMA (aX from sXt); in-wave LSTM update ----
    {
      s8v aX[4];
      #pragma unroll
      for (int kc = 0; kc < 4; ++kc)
        aX[kc] = *(const s8v*)((const char*)sXt + (lane&15)*528 + kc*64 + g*16);
      f4v acc[4];
      #pragma unroll
      for (int gg = 0; gg < 4; ++gg) acc[gg] = (f4v){0.f,0.f,0.f,0.f};
      #pragma unroll
      for (int kc = 0; kc < 8; ++kc){
        s8v af = (kc < 4) ? aX[kc] : aT[kc];
        #pragma unroll
        for (int gg = 0; gg < 4; ++gg) acc[gg] = MFMA16(af, bwC[gg][kc], acc[gg]);
      }
      if (lane < 32){
        int mb = g*4;
        #pragma unroll
        for (int j = 0; j < 4; ++j){
          int m = mb + j;
          float gi = acc[0][j] + bias_r[0];
          float gf = acc[1][j] + bias_r[1];
          float gg2 = acc[2][j] + bias_r[2];
          float go = acc[3][j] + bias_r[3];
          float cold = c_r[j];
          float cn = fast_sig(gf)*cold + fast_sig(gi)*fast_tanh(gg2);
          float hn = fast_sig(go)*fast_tanh(cn);
          c_r[j] = cn;
          sAB[m*264 + n16] = f2bf(cn);
          sAB[m*264 + 128 + n16] = f2bf(hn);
          Hsb[((size_t)(bbase + m)*NW + t)*NH + n16] = f2bf(hn);
        }
      }
      xrow[wave*128 + lane] = xn0;
      xrow[wave*128 + 64 + lane] = xn1;
    }
    __syncthreads();  // 3
  }
}

// =========================== decoder ===========================
__global__ __launch_bounds__(512, 2) void k_dec(
    const float* __restrict__ taW1, const float* __restrict__ tab1,
    const float* __restrict__ taW2,
    const float* __restrict__ decWih, const float* __restrict__ decWhh,
    const float* __restrict__ decbih, const float* __restrict__ decbhh,
    const float* __restrict__ l1W, const float* __restrict__ l1b,
    const float* __restrict__ l2W, const float* __restrict__ l2b,
    const float* __restrict__ l3W, const float* __restrict__ l3b,
    const ushort* __restrict__ Edec, const uchar* __restrict__ HsT8,
    float* __restrict__ out){
  __shared__ __align__(16) ushort sVp[65536];    // E_dec slice [bb][w][h] f16, slot-XOR
  __shared__ __align__(16) ushort sAB[16*264];   // [d|ds] bf16
  __shared__ __align__(16) ushort sCT[16*136];   // ct bf16
  __shared__ __align__(16) ushort vd_h[8*128];   // exp(2*vd) f16
  __shared__ __align__(16) uchar  lb8[8*64];     // beta*16 fp8
  __shared__ __align__(16) float  op_s[8][8];    // per-wave l3.o partials
  __shared__ __align__(16) float  yt_s[8];

  const int tid = threadIdx.x, lane = tid & 63, wave = tid >> 6, g = lane >> 4;
  const int bbase = blockIdx.x * 8;
  const int n16 = wave*16 + (lane & 15);

  for (int i = tid; i < 16*264; i += 512) sAB[i] = 0;
  for (int i = tid; i < 16*136; i += 512) sCT[i] = 0;
  {
    const ushort* vp0 = Edec + (size_t)bbase*NW*NH;
    #pragma unroll
    for (int k = 0; k < 16; ++k){
      int c = tid + k*512;
      int w = (c >> 4) & 63, s = c & 15;
      uint4 v = *(const uint4*)(vp0 + (size_t)c*8);
      *(uint4*)((char*)sVp + (c >> 4)*256 + ((s ^ (w & 15)) << 4)) = v;
    }
  }
  float bias_r[4], wih_r[4];
  #pragma unroll
  for (int gg = 0; gg < 4; ++gg){
    bias_r[gg] = decbih[gg*128 + n16] + decbhh[gg*128 + n16];
    wih_r[gg]  = decWih[gg*128 + n16];
  }
  float tab1_r = tab1[n16];
  float l2b_r  = l2b[n16];
  float l3w_r  = l3W[n16];
  float l1w0 = l1W[0], l1b0 = l1b[0], l3b0 = l3b[0];
  float cds_r[4] = {0.f, 0.f, 0.f, 0.f};
  s8v bwA[8];
  #pragma unroll
  for (int kc = 0; kc < 8; ++kc)
    bwA[kc] = packW(taW1 + n16*384 + 128 + kc*32 + g*8);
  s8v bwD[4][4];
  #pragma unroll
  for (int gg = 0; gg < 4; ++gg){
    int j = gg*128 + n16;
    #pragma unroll
    for (int kc = 0; kc < 4; ++kc)
      bwD[gg][kc] = packW(decWhh + j*128 + kc*32 + g*8);
  }
  s8v bwF[8];
  #pragma unroll
  for (int kc = 0; kc < 8; ++kc)
    bwF[kc] = packW(l2W + n16*256 + kc*32 + g*8);
  H8 w2df[4];
  #pragma unroll
  for (int kb = 0; kb < 4; ++kb)
    #pragma unroll
    for (int i = 0; i < 8; ++i)
      w2df[kb].v[i] = (_Float16)taW2[kb*32 + g*8 + i];
  float l1w[8];
  #pragma unroll
  for (int ht = 0; ht < 8; ++ht) l1w[ht] = l1W[1 + ht*16 + (lane & 15)];
  __syncthreads();

  for (int t = 0; t < NW; ++t){
    // ---- A: vd via MFMA from [d|ds] ----
    s8v aT[8];
    #pragma unroll
    for (int kc = 0; kc < 8; ++kc)
      aT[kc] = *(const s8v*)((const char*)sAB + (lane&15)*528 + kc*64 + g*16);
    {
      f4v acc = {0.f,0.f,0.f,0.f};
      #pragma unroll
      for (int kc = 0; kc < 8; ++kc) acc = MFMA16(aT[kc], bwA[kc], acc);
      if (lane < 32){
        int mb = g*4;
        #pragma unroll
        for (int j = 0; j < 4; ++j) vd_h[(mb+j)*128 + n16] = expo_h(acc[j] + tab1_r);
      }
    }
    __syncthreads();  // 1

    // ---- B+C (wave-local): softmax over w, then ct (fp8 MFMA) + yt ----
    {
      int bb = wave;
      // early-issue Hs fp8 B-frags: 64KB/block slice -> fully L2-resident
      const uchar* hb8 = HsT8 + (size_t)(bbase + bb)*NH*NW;
      U8 hbf[8][2];
      #pragma unroll
      for (int ht = 0; ht < 8; ++ht){
        int h = ht*16 + (lane & 15);
        hbf[ht][0].u2 = *(const uint2*)(hb8 + h*64 + g*8);
        hbf[ht][1].u2 = *(const uint2*)(hb8 + h*64 + 32 + g*8);
      }
      const char* Eb = (const char*)sVp + bb*16384;
      H8 sv[4];
      #pragma unroll
      for (int kb = 0; kb < 4; ++kb)
        sv[kb].u4 = *(const uint4*)((const char*)vd_h + bb*256 + kb*64 + g*16);
      __half2 one2 = __float2half2_rn(1.f);
      f4v Mc[4];
      #pragma unroll
      for (int wt = 0; wt < 4; ++wt){
        int w = wt*16 + (lane & 15);
        const char* rowp = Eb + w*256;
        f4v acc = {0.f,0.f,0.f,0.f};
        #pragma unroll
        for (int kb = 0; kb < 4; ++kb){
          H8 e, a;
          e.v = *(const h8v*)(rowp + (((kb*4 + g) ^ (w & 15)) << 4));
          #pragma unroll
          for (int q = 0; q < 4; ++q) a.h2[q] = h2rcp(__hfma2(e.h2[q], sv[kb].h2[q], one2));
          acc = MFMAH(a.v, w2df[kb].v, acc);
        }
        Mc[wt] = acc;
      }
      float xs[4][4]; float ssum = 0.f;
      #pragma unroll
      for (int wt = 0; wt < 4; ++wt)
        #pragma unroll
        for (int r = 0; r < 4; ++r){ float x = __expf(-2.f*Mc[wt][r]); xs[wt][r] = x; ssum += x; }
      ssum += __shfl_xor(ssum, 16, 64);
      ssum += __shfl_xor(ssum, 32, 64);
      float inv16 = 16.f * __builtin_amdgcn_rcpf(ssum);
      if ((lane & 15) == 0){
        #pragma unroll
        for (int wt = 0; wt < 4; ++wt){
          int w0 = wt*16 + g*4;
          *(uint*)(lb8 + bb*64 + w0) =
            f2fp8x4(xs[wt][0]*inv16, xs[wt][1]*inv16, xs[wt][2]*inv16, xs[wt][3]*inv16);
        }
      }
      // same-wave: beta back as fp8 A-frags
      U8 ba0, ba1;
      ba0.u2 = *(const uint2*)(lb8 + bb*64 + g*8);
      ba1.u2 = *(const uint2*)(lb8 + bb*64 + 32 + g*8);
      float p = 0.f;
      #pragma unroll
      for (int ht = 0; ht < 8; ++ht){
        f4v acc = {0.f,0.f,0.f,0.f};
        acc = MFMA8(ba0.v, hbf[ht][0].v, acc);
        acc = MFMA8(ba1.v, hbf[ht][1].v, acc);
        float ctv = acc[0] * (1.f/256.f);
        if (lane < 16) sCT[bb*136 + ht*16 + (lane&15)] = f2bf(ctv);
        p += l1w[ht] * ctv;
      }
      p += __shfl_xor(p, 1, 64);
      p += __shfl_xor(p, 2, 64);
      p += __shfl_xor(p, 4, 64);
      p += __shfl_xor(p, 8, 64);
      if (lane == 0) yt_s[bb] = p + l1b0;
    }
    __syncthreads();  // 2

    // ---- D: gates via MFMA + in-wave update (out_prev from op_s) ----
    {
      f4v g4[4];
      #pragma unroll
      for (int gg = 0; gg < 4; ++gg) g4[gg] = (f4v){0.f,0.f,0.f,0.f};
      #pragma unroll
      for (int kc = 0; kc < 4; ++kc){
        #pragma unroll
        for (int gg = 0; gg < 4; ++gg) g4[gg] = MFMA16(aT[kc], bwD[gg][kc], g4[gg]);
      }
      if (lane < 32){
        int mb = g*4;
        float4 so = make_float4(0.f, 0.f, 0.f, 0.f);
        #pragma unroll
        for (int w = 0; w < 8; ++w){
          float4 v = *(const float4*)((const char*)op_s + w*32 + g*16);
          so.x += v.x; so.y += v.y; so.z += v.z; so.w += v.w;
        }
        float soa[4] = {so.x, so.y, so.z, so.w};
        #pragma unroll
        for (int j = 0; j < 4; ++j){
          int m = mb + j;
          float outp = (t == 0) ? 0.f : fast_sig(soa[j] + l3b0);
          float yt = yt_s[m] + l1w0*outp;
          float gi = g4[0][j] + bias_r[0] + wih_r[0]*yt;
          float gf = g4[1][j] + bias_r[1] + wih_r[1]*yt;
          float gg2 = g4[2][j] + bias_r[2] + wih_r[2]*yt;
          float go = g4[3][j] + bias_r[3] + wih_r[3]*yt;
          float cold = cds_r[j];
          float cn = fast_sig(gf)*cold + fast_sig(gi)*fast_tanh(gg2);
          float hn = fast_sig(go)*fast_tanh(cn);
          cds_r[j] = cn;
          sAB[m*264 + n16] = f2bf(hn);
          sAB[m*264 + 128 + n16] = f2bf(cn);
        }
      }
    }
    __syncthreads();  // 3

    // ---- F: o = [ct|d_new] @ l2W^T + l2b via MFMA; l3.o partials ----
    {
      f4v of = {0.f,0.f,0.f,0.f};
      #pragma unroll
      for (int kc = 0; kc < 4; ++kc){
        s8v af = *(const s8v*)((const char*)sCT + (lane&15)*272 + kc*64 + g*16);
        of = MFMA16(af, bwF[kc], of);
      }
      #pragma unroll
      for (int kc = 4; kc < 8; ++kc){
        s8v af = *(const s8v*)((const char*)sAB + (lane&15)*528 + (kc-4)*64 + g*16);
        of = MFMA16(af, bwF[kc], of);
      }
      float p0 = l3w_r*(of[0] + l2b_r);
      float p1 = l3w_r*(of[1] + l2b_r);
      float p2 = l3w_r*(of[2] + l2b_r);
      float p3 = l3w_r*(of[3] + l2b_r);
      #pragma unroll
      for (int off = 1; off <= 8; off <<= 1){
        p0 += __shfl_xor(p0, off, 64);
        p1 += __shfl_xor(p1, off, 64);
        p2 += __shfl_xor(p2, off, 64);
        p3 += __shfl_xor(p3, off, 64);
      }
      if ((lane & 15) == 0 && lane < 32){
        *(float4*)((char*)op_s + wave*32 + g*16) = make_float4(p0, p1, p2, p3);
      }
    }
    // no trailing barrier: op_s consumed after bar1+bar2 of t+1
  }
  __syncthreads();
  if (tid < 8){
    float s = 0.f;
    #pragma unroll
    for (int w = 0; w < 8; ++w) s += op_s[w][tid];
    out[bbase + tid] = fast_sig(s + l3b0);
  }
}

extern "C" void kernel_launch(void* const* d_in, const int* in_sizes, int n_in,
                              void* d_out, int out_size, void* d_ws, size_t ws_size,
                              hipStream_t stream){
  const float* X      = (const float*)d_in[0];
  const float* iaW1   = (const float*)d_in[1];
  const float* iab1   = (const float*)d_in[2];
  const float* iaW2   = (const float*)d_in[3];
  const float* encWih = (const float*)d_in[5];
  const float* encWhh = (const float*)d_in[6];
  const float* encbih = (const float*)d_in[7];
  const float* encbhh = (const float*)d_in[8];
  const float* taW1   = (const float*)d_in[9];
  const float* tab1   = (const float*)d_in[10];
  const float* taW2   = (const float*)d_in[11];
  const float* decWih = (const float*)d_in[13];
  const float* decWhh = (const float*)d_in[14];
  const float* decbih = (const float*)d_in[15];
  const float* decbhh = (const float*)d_in[16];
  const float* l1W    = (const float*)d_in[17];
  const float* l1b    = (const float*)d_in[18];
  const float* l2W    = (const float*)d_in[19];
  const float* l2b    = (const float*)d_in[20];
  const float* l3W    = (const float*)d_in[21];
  const float* l3b    = (const float*)d_in[22];

  char* ws = (char*)d_ws;
  ushort* Eenc = (ushort*)(ws);                // 32MB f16 [b][f][w]; aliased by Edec later
  ushort* Hsb  = (ushort*)(ws + 33554432);     // 32MB bf16 [b][w][h]
  uchar*  HsT8 = (uchar*)(ws + 2*33554432);    // 16MB fp8  [b][h][w] (x16 scale)
  ushort* Edec = Eenc;

  k_upre<<<dim3(2048), dim3(256), 0, stream>>>(X, iaW1, Eenc);
  k_enc<<<dim3(256), dim3(512), 0, stream>>>(X, iaW1, iab1, iaW2,
                                             encWih, encWhh, encbih, encbhh,
                                             Eenc, Hsb);
  k_vpre<<<dim3(2048), dim3(256), 0, stream>>>(Hsb, taW1, Edec, HsT8);
  k_dec<<<dim3(256), dim3(512), 0, stream>>>(taW1, tab1, taW2,
                                             decWih, decWhh, decbih, decbhh,
                                             l1W, l1b, l2W, l2b, l3W, l3b,
                                             Edec, HsT8, (float*)d_out);
}